// Round 16
// baseline (270.430 us; speedup 1.0000x reference)
//
#include <hip/hip_runtime.h>

#define NN 50000
#define NE 600000
#define F 128

typedef __attribute__((ext_vector_type(4))) float f4;
typedef __attribute__((ext_vector_type(4))) float f32x4;
typedef __bf16 bf16x8 __attribute__((ext_vector_type(8)));
typedef short short8v __attribute__((ext_vector_type(8)));
typedef unsigned short u16x8 __attribute__((ext_vector_type(8)));

__device__ inline ushort f2bf(float f) {
    uint u = __builtin_bit_cast(uint, f);
    uint r = (u + 0x7FFFu + ((u >> 16) & 1u)) >> 16;
    return (ushort)r;
}
__device__ inline float bf2f(ushort u) {
    uint t = ((uint)u) << 16;
    return __builtin_bit_cast(float, t);
}

// ---------------- graph prep ----------------

__global__ void count_deg(const int* __restrict__ dst, int* __restrict__ deg, int E) {
    int e = blockIdx.x * blockDim.x + threadIdx.x;
    if (e < E) atomicAdd(&deg[dst[e]], 1);
}

__global__ __launch_bounds__(1024) void scan_part1(const int* __restrict__ deg,
                                                   int* __restrict__ bsum, int N) {
    __shared__ int ws[16];
    int tid = threadIdx.x;
    int idx = blockIdx.x * 1024 + tid;
    int v = (idx < N) ? deg[idx] : 0;
    #pragma unroll
    for (int o = 32; o; o >>= 1) v += __shfl_down(v, o);
    if ((tid & 63) == 0) ws[tid >> 6] = v;
    __syncthreads();
    if (tid < 64) {
        int t = (tid < 16) ? ws[tid] : 0;
        #pragma unroll
        for (int o = 8; o; o >>= 1) t += __shfl_down(t, o);
        if (tid == 0) bsum[blockIdx.x] = t;
    }
}

__global__ __launch_bounds__(1024) void scan_part3(const int* __restrict__ deg,
                                                   const int* __restrict__ bsum,
                                                   int* __restrict__ off,
                                                   int* __restrict__ cur,
                                                   float* __restrict__ recip,
                                                   int N, int NB) {
    __shared__ int wsum[16];
    __shared__ int sbase;
    int tid = threadIdx.x;
    int wid = tid >> 6;
    int lane = tid & 63;
    if (tid < 64) {
        int v = (tid < NB) ? bsum[tid] : 0;
        int x = v;
        #pragma unroll
        for (int o = 1; o < 64; o <<= 1) {
            int t = __shfl_up(x, o);
            if (lane >= o) x += t;
        }
        if (tid == blockIdx.x) sbase = x - v;
    }
    int idx = blockIdx.x * 1024 + tid;
    int v = (idx < N) ? deg[idx] : 0;
    int x = v;
    #pragma unroll
    for (int o = 1; o < 64; o <<= 1) {
        int t = __shfl_up(x, o);
        if (lane >= o) x += t;
    }
    if (lane == 63) wsum[wid] = x;
    __syncthreads();
    if (tid == 0) {
        int a = 0;
        #pragma unroll
        for (int w = 0; w < 16; ++w) { int t = wsum[w]; wsum[w] = a; a += t; }
    }
    __syncthreads();
    int incl = x + wsum[wid];
    if (idx < N) {
        int start = sbase + incl - v;
        off[idx] = start;
        cur[idx] = start;
        recip[idx] = 1.0f / (float)max(v, 1);
    }
}

__global__ void fill_csr(const int* __restrict__ src, const int* __restrict__ dst,
                         int* __restrict__ cur, int* __restrict__ csr, int E) {
    int e = blockIdx.x * blockDim.x + threadIdx.x;
    if (e < E) {
        int pos = atomicAdd(&cur[dst[e]], 1);
        csr[pos] = src[e];
    }
}

// ---------------- weight prep: Bt[col][k] bf16 for all 3 layers ----------------

__global__ __launch_bounds__(256) void wt_prep(const float* __restrict__ W1s, const float* __restrict__ W1n,
                                               const float* __restrict__ W2s, const float* __restrict__ W2n,
                                               const float* __restrict__ W3s, const float* __restrict__ W3n,
                                               ushort* __restrict__ Bt1, ushort* __restrict__ Bt2,
                                               ushort* __restrict__ Bt3) {
    int layer = blockIdx.y;
    const float* Ws = (layer == 0) ? W1s : (layer == 1) ? W2s : W3s;
    const float* Wn = (layer == 0) ? W1n : (layer == 1) ? W2n : W3n;
    ushort* Bt = (layer == 0) ? Bt1 : (layer == 1) ? Bt2 : Bt3;
    int col = blockIdx.x;
    int k = threadIdx.x;
    float v = (k < 128) ? Ws[k * 128 + col] : Wn[(k - 128) * 128 + col];
    Bt[col * 256 + k] = f2bf(v);
}

// ---------------- f32 -> bf16 feature convert ----------------

__global__ __launch_bounds__(256) void to_bf16(const float* __restrict__ in,
                                               ushort* __restrict__ out, int n8) {
    int i = blockIdx.x * 256 + threadIdx.x;
    if (i < n8) {
        const f4* p = (const f4*)in + (size_t)i * 2;
        f4 a = p[0], b = p[1];
        short8v w;
        w[0] = (short)f2bf(a[0]); w[1] = (short)f2bf(a[1]);
        w[2] = (short)f2bf(a[2]); w[3] = (short)f2bf(a[3]);
        w[4] = (short)f2bf(b[0]); w[5] = (short)f2bf(b[1]);
        w[6] = (short)f2bf(b[2]); w[7] = (short)f2bf(b[3]);
        ((short8v*)out)[i] = w;
    }
}

// ---------------- fused SAGE layer: out = act([x | mean(x,nbrs)] @ Bt^T + b) ----------------
// 32 nodes x 128 cols per block, 256 threads (4 waves).
// Gather = NODE-PER-THREAD x col-chunk: thread t owns (node t&31, 16-col
// chunk t>>5). Consecutive lanes hit DIFFERENT random rows -> per-instruction
// coalescing cannot collapse the requests -> ~8x memory-level parallelism vs
// group-per-node. All 8 chunks of a node live in the SAME block (same XCD L2)
// so each 128B line is fetched once per block. 4-edge rounds (8 x 16B loads
// in flight/thread), clamp+mask tail. f32 accum -> bf16 -> swizzled LDS
// (k 128..255). Phase 2: 4 waves x (4 col-tiles x 8 k-steps) MFMA.
// Output bf16 (layers 1,2) or f32 (layer 3). No aliasing: out != xb.

template <int RELU, int OUTBF>
__global__ __launch_bounds__(256) void sage_layer(const ushort* __restrict__ xb,
                                                  const int* __restrict__ off,
                                                  const int* __restrict__ deg,
                                                  const float* __restrict__ recip,
                                                  const int* __restrict__ csr,
                                                  const ushort* __restrict__ Bt,
                                                  const float* __restrict__ bias,
                                                  void* __restrict__ outp, int N) {
    __shared__ ushort sa[32 * 256];  // 16 KB, [row][k], XOR-swizzled
    int tid = threadIdx.x;
    int r0 = blockIdx.x * 32;

    // ---- stage x rows (k 0..127): 32 B per thread ----
    {
        int row = tid >> 3;
        int c = tid & 7;
        int grow = r0 + row;
        uint sw = ((uint)row & 7u) << 4;
        uint base = (uint)(row * 512 + c * 32);
        short8v w0 = (short8v)0, w1 = (short8v)0;
        if (grow < N) {
            const short8v* sp = (const short8v*)&xb[(size_t)grow * 128 + c * 16];
            w0 = sp[0]; w1 = sp[1];
        }
        *(short8v*)((char*)sa + (base ^ sw)) = w0;
        *(short8v*)((char*)sa + ((base + 16) ^ sw)) = w1;
    }

    // ---- gather-mean into LDS (k 128..255): node-per-thread x 16-col chunk ----
    {
        int row = tid & 31;      // node within block
        int ch = tid >> 5;       // 0..7, 16-col chunk
        int node = r0 + row;
        const ushort* xpb = xb + (size_t)ch * 16;  // this thread's col slice
        float a[16];
        #pragma unroll
        for (int j = 0; j < 16; ++j) a[j] = 0.f;
        if (node < N) {
            int start = off[node];
            int d = deg[node];
            int dm1 = (d > 0) ? d - 1 : 0;
            for (int i = 0; i < d; i += 4) {
                int s[4];
                #pragma unroll
                for (int u = 0; u < 4; ++u) {
                    int idx = i + u;
                    s[u] = csr[start + ((idx < dm1) ? idx : dm1)];
                }
                u16x8 v0[4], v1[4];
                #pragma unroll
                for (int u = 0; u < 4; ++u) {
                    const ushort* rp = xpb + (size_t)s[u] * 128;
                    v0[u] = *(const u16x8*)rp;
                    v1[u] = *(const u16x8*)(rp + 8);
                }
                #pragma unroll
                for (int u = 0; u < 4; ++u) {
                    float m = (i + u < d) ? 1.f : 0.f;
                    #pragma unroll
                    for (int j = 0; j < 8; ++j) {
                        a[j] += m * bf2f(v0[u][j]);
                        a[8 + j] += m * bf2f(v1[u][j]);
                    }
                }
            }
            float r = recip[node];
            #pragma unroll
            for (int j = 0; j < 16; ++j) a[j] *= r;
        }
        short8v w0, w1;
        #pragma unroll
        for (int j = 0; j < 8; ++j) {
            w0[j] = (short)f2bf(a[j]);
            w1[j] = (short)f2bf(a[8 + j]);
        }
        uint sw = ((uint)row & 7u) << 4;
        uint addr = (uint)(row * 512 + 256 + ch * 32);
        *(short8v*)((char*)sa + (addr ^ sw)) = w0;
        *(short8v*)((char*)sa + ((addr + 16) ^ sw)) = w1;
    }
    __syncthreads();

    int lane = tid & 63;
    int wid = tid >> 6;
    int wr = wid & 1;        // row half
    int wc = wid >> 1;       // col quarter (64 cols)
    int l15 = lane & 15;
    int lg = lane >> 4;      // k-group

    // ---- A fragments (8 k-steps) ----
    int arow = wr * 16 + l15;
    uint abase = (uint)(arow * 512 + lg * 16);
    uint asw = ((uint)arow & 7u) << 4;
    bf16x8 a[8];
    #pragma unroll
    for (int ks = 0; ks < 8; ++ks) {
        a[ks] = *(const bf16x8*)((const char*)sa + ((abase + (uint)ks * 64) ^ asw));
    }

    // ---- MFMA: 4 col-tiles x 8 k-steps ----
    f32x4 acc[4];
    #pragma unroll
    for (int ct = 0; ct < 4; ++ct) acc[ct] = (f32x4)0.f;

    #pragma unroll
    for (int ct = 0; ct < 4; ++ct) {
        int bcol = wc * 64 + ct * 16 + l15;
        const ushort* bp = Bt + bcol * 256 + lg * 8;
        #pragma unroll
        for (int ks = 0; ks < 8; ++ks) {
            bf16x8 b = *(const bf16x8*)(bp + ks * 32);
            acc[ct] = __builtin_amdgcn_mfma_f32_16x16x32_bf16(a[ks], b, acc[ct], 0, 0, 0);
        }
    }

    // ---- epilogue: C/D layout col=lane&15, row=(lane>>4)*4+r ----
    int crow = r0 + wr * 16 + lg * 4;
    #pragma unroll
    for (int ct = 0; ct < 4; ++ct) {
        int col = wc * 64 + ct * 16 + l15;
        float bv = bias[col];
        #pragma unroll
        for (int r = 0; r < 4; ++r) {
            int row = crow + r;
            if (row < N) {
                float v = acc[ct][r] + bv;
                if (RELU) v = fmaxf(v, 0.f);
                if (OUTBF) ((ushort*)outp)[(size_t)row * 128 + col] = f2bf(v);
                else       ((float*)outp)[(size_t)row * 128 + col] = v;
            }
        }
    }
}

// ---------------- launch ----------------

extern "C" void kernel_launch(void* const* d_in, const int* in_sizes, int n_in,
                              void* d_out, int out_size, void* d_ws, size_t ws_size,
                              hipStream_t stream) {
    const float* feat = (const float*)d_in[0];
    const int* src = (const int*)d_in[1];
    const int* dst = (const int*)d_in[2];
    const float* W1s = (const float*)d_in[3];
    const float* W1n = (const float*)d_in[4];
    const float* b1 = (const float*)d_in[5];
    const float* W2s = (const float*)d_in[6];
    const float* W2n = (const float*)d_in[7];
    const float* b2 = (const float*)d_in[8];
    const float* W3s = (const float*)d_in[9];
    const float* W3n = (const float*)d_in[10];
    const float* b3 = (const float*)d_in[11];
    float* out = (float*)d_out;

    const int N = NN, E = NE;
    const int NB = (N + 1023) / 1024;

    char* p = (char*)d_ws;
    auto alloc = [&](size_t bytes) {
        char* q = p;
        p += (bytes + 255) & ~(size_t)255;
        return q;
    };
    int* deg = (int*)alloc((size_t)N * 4);
    int* off = (int*)alloc((size_t)N * 4);
    int* cur = (int*)alloc((size_t)N * 4);
    float* recip = (float*)alloc((size_t)N * 4);
    int* bsum = (int*)alloc(64 * 4);
    int* csr = (int*)alloc((size_t)E * 4);
    ushort* xb0 = (ushort*)alloc((size_t)N * F * 2);
    ushort* h1b = (ushort*)alloc((size_t)N * F * 2);
    ushort* h2b = (ushort*)alloc((size_t)N * F * 2);
    ushort* Bt1 = (ushort*)alloc(128 * 256 * 2);
    ushort* Bt2 = (ushort*)alloc(128 * 256 * 2);
    ushort* Bt3 = (ushort*)alloc(128 * 256 * 2);

    wt_prep<<<dim3(128, 3), 256, 0, stream>>>(W1s, W1n, W2s, W2n, W3s, W3n, Bt1, Bt2, Bt3);
    to_bf16<<<(N * F / 8 + 255) / 256, 256, 0, stream>>>(feat, xb0, N * F / 8);

    hipMemsetAsync(deg, 0, (size_t)N * 4, stream);
    count_deg<<<(E + 255) / 256, 256, 0, stream>>>(dst, deg, E);
    scan_part1<<<NB, 1024, 0, stream>>>(deg, bsum, N);
    scan_part3<<<NB, 1024, 0, stream>>>(deg, bsum, off, cur, recip, N, NB);
    fill_csr<<<(E + 255) / 256, 256, 0, stream>>>(src, dst, cur, csr, E);

    int grid = (N + 31) / 32;

    sage_layer<1, 1><<<grid, 256, 0, stream>>>(xb0, off, deg, recip, csr, Bt1, b1, h1b, N);
    sage_layer<1, 1><<<grid, 256, 0, stream>>>(h1b, off, deg, recip, csr, Bt2, b2, h2b, N);
    sage_layer<0, 0><<<grid, 256, 0, stream>>>(h2b, off, deg, recip, csr, Bt3, b3, out, N);
}

// Round 17
// 241.864 us; speedup vs baseline: 1.1181x; 1.1181x over previous
//
#include <hip/hip_runtime.h>

#define NN 50000
#define NE 600000
#define F 128

typedef __attribute__((ext_vector_type(4))) float f4;
typedef __attribute__((ext_vector_type(4))) float f32x4;
typedef __bf16 bf16x8 __attribute__((ext_vector_type(8)));
typedef short short8v __attribute__((ext_vector_type(8)));
typedef unsigned short u16x8 __attribute__((ext_vector_type(8)));

__device__ inline ushort f2bf(float f) {
    uint u = __builtin_bit_cast(uint, f);
    uint r = (u + 0x7FFFu + ((u >> 16) & 1u)) >> 16;
    return (ushort)r;
}
__device__ inline float bf2f(ushort u) {
    uint t = ((uint)u) << 16;
    return __builtin_bit_cast(float, t);
}

// ---------------- graph prep ----------------

__global__ void count_deg(const int* __restrict__ dst, int* __restrict__ deg, int E) {
    int e = blockIdx.x * blockDim.x + threadIdx.x;
    if (e < E) atomicAdd(&deg[dst[e]], 1);
}

__global__ __launch_bounds__(1024) void scan_part1(const int* __restrict__ deg,
                                                   int* __restrict__ bsum, int N) {
    __shared__ int ws[16];
    int tid = threadIdx.x;
    int idx = blockIdx.x * 1024 + tid;
    int v = (idx < N) ? deg[idx] : 0;
    #pragma unroll
    for (int o = 32; o; o >>= 1) v += __shfl_down(v, o);
    if ((tid & 63) == 0) ws[tid >> 6] = v;
    __syncthreads();
    if (tid < 64) {
        int t = (tid < 16) ? ws[tid] : 0;
        #pragma unroll
        for (int o = 8; o; o >>= 1) t += __shfl_down(t, o);
        if (tid == 0) bsum[blockIdx.x] = t;
    }
}

__global__ __launch_bounds__(1024) void scan_part3(const int* __restrict__ deg,
                                                   const int* __restrict__ bsum,
                                                   int* __restrict__ off,
                                                   int* __restrict__ cur,
                                                   float* __restrict__ recip,
                                                   int N, int NB) {
    __shared__ int wsum[16];
    __shared__ int sbase;
    int tid = threadIdx.x;
    int wid = tid >> 6;
    int lane = tid & 63;
    if (tid < 64) {
        int v = (tid < NB) ? bsum[tid] : 0;
        int x = v;
        #pragma unroll
        for (int o = 1; o < 64; o <<= 1) {
            int t = __shfl_up(x, o);
            if (lane >= o) x += t;
        }
        if (tid == blockIdx.x) sbase = x - v;
    }
    int idx = blockIdx.x * 1024 + tid;
    int v = (idx < N) ? deg[idx] : 0;
    int x = v;
    #pragma unroll
    for (int o = 1; o < 64; o <<= 1) {
        int t = __shfl_up(x, o);
        if (lane >= o) x += t;
    }
    if (lane == 63) wsum[wid] = x;
    __syncthreads();
    if (tid == 0) {
        int a = 0;
        #pragma unroll
        for (int w = 0; w < 16; ++w) { int t = wsum[w]; wsum[w] = a; a += t; }
    }
    __syncthreads();
    int incl = x + wsum[wid];
    if (idx < N) {
        int start = sbase + incl - v;
        off[idx] = start;
        cur[idx] = start;
        recip[idx] = 1.0f / (float)max(v, 1);
    }
}

__global__ void fill_csr(const int* __restrict__ src, const int* __restrict__ dst,
                         int* __restrict__ cur, int* __restrict__ csr, int E) {
    int e = blockIdx.x * blockDim.x + threadIdx.x;
    if (e < E) {
        int pos = atomicAdd(&cur[dst[e]], 1);
        csr[pos] = src[e];
    }
}

// ---------------- weight prep: Bt[col][k] bf16 for all 3 layers ----------------

__global__ __launch_bounds__(256) void wt_prep(const float* __restrict__ W1s, const float* __restrict__ W1n,
                                               const float* __restrict__ W2s, const float* __restrict__ W2n,
                                               const float* __restrict__ W3s, const float* __restrict__ W3n,
                                               ushort* __restrict__ Bt1, ushort* __restrict__ Bt2,
                                               ushort* __restrict__ Bt3) {
    int layer = blockIdx.y;
    const float* Ws = (layer == 0) ? W1s : (layer == 1) ? W2s : W3s;
    const float* Wn = (layer == 0) ? W1n : (layer == 1) ? W2n : W3n;
    ushort* Bt = (layer == 0) ? Bt1 : (layer == 1) ? Bt2 : Bt3;
    int col = blockIdx.x;
    int k = threadIdx.x;
    float v = (k < 128) ? Ws[k * 128 + col] : Wn[(k - 128) * 128 + col];
    Bt[col * 256 + k] = f2bf(v);
}

// ---------------- f32 -> bf16 feature convert ----------------

__global__ __launch_bounds__(256) void to_bf16(const float* __restrict__ in,
                                               ushort* __restrict__ out, int n8) {
    int i = blockIdx.x * 256 + threadIdx.x;
    if (i < n8) {
        const f4* p = (const f4*)in + (size_t)i * 2;
        f4 a = p[0], b = p[1];
        short8v w;
        w[0] = (short)f2bf(a[0]); w[1] = (short)f2bf(a[1]);
        w[2] = (short)f2bf(a[2]); w[3] = (short)f2bf(a[3]);
        w[4] = (short)f2bf(b[0]); w[5] = (short)f2bf(b[1]);
        w[6] = (short)f2bf(b[2]); w[7] = (short)f2bf(b[3]);
        ((short8v*)out)[i] = w;
    }
}

// ---------------- fused SAGE layer: out = act([x | mean(x,nbrs)] @ Bt^T + b) ----------------
// 32 nodes x 128 cols per block, 256 threads (4 waves). NO x-staging: the
// x-half A-fragments are 16B-contiguous in global memory (L1/L2-hit rows the
// block owns), so only the gathered mean goes through LDS (8 KB, swizzled).
// Schedule: gather-mean (16-lane groups, nodes g/g+16, 8-edge rounds) ->
// x-half MFMA (overlaps other waves' gather tails) -> barrier ->
// mean-half MFMA -> epilogue. Output bf16 (layers 1,2) or f32 (layer 3).

template <int RELU, int OUTBF>
__global__ __launch_bounds__(256) void sage_layer(const ushort* __restrict__ xb,
                                                  const int* __restrict__ off,
                                                  const int* __restrict__ deg,
                                                  const float* __restrict__ recip,
                                                  const int* __restrict__ csr,
                                                  const ushort* __restrict__ Bt,
                                                  const float* __restrict__ bias,
                                                  void* __restrict__ outp, int N) {
    __shared__ ushort sm[32 * 128];  // 8 KB mean rows [row][k], XOR-swizzled
    int tid = threadIdx.x;
    int r0 = blockIdx.x * 32;

    // ---- gather-mean into LDS: 16 lanes/node, nodes g and g+16 ----
    {
        int g = tid >> 4;
        int l16 = tid & 15;
        const ushort* xpb = xb + (size_t)l16 * 8;  // this lane's 8-col slice
        #pragma unroll
        for (int rep = 0; rep < 2; ++rep) {
            int row = g + rep * 16;
            int node = r0 + row;
            float a[8] = {0.f, 0.f, 0.f, 0.f, 0.f, 0.f, 0.f, 0.f};
            if (node < N) {
                int start = off[node];
                int d = deg[node];
                int nfull = d & ~7;
                int i = 0;
                for (; i < nfull; i += 8) {
                    int s[8];
                    #pragma unroll
                    for (int u = 0; u < 8; ++u) s[u] = csr[start + i + u];
                    u16x8 v[8];
                    #pragma unroll
                    for (int u = 0; u < 8; ++u) v[u] = *(const u16x8*)(xpb + (size_t)s[u] * 128);
                    #pragma unroll
                    for (int u = 0; u < 8; ++u) {
                        #pragma unroll
                        for (int j = 0; j < 8; ++j) a[j] += bf2f(v[u][j]);
                    }
                }
                if (i < d) {
                    int dm1 = d - 1;
                    int s[8];
                    #pragma unroll
                    for (int u = 0; u < 8; ++u) {
                        int idx = i + u;
                        s[u] = csr[start + ((idx < dm1) ? idx : dm1)];
                    }
                    u16x8 v[8];
                    #pragma unroll
                    for (int u = 0; u < 8; ++u) v[u] = *(const u16x8*)(xpb + (size_t)s[u] * 128);
                    #pragma unroll
                    for (int u = 0; u < 8; ++u) {
                        float m = (i + u < d) ? 1.f : 0.f;
                        #pragma unroll
                        for (int j = 0; j < 8; ++j) a[j] += m * bf2f(v[u][j]);
                    }
                }
                float r = recip[node];
                #pragma unroll
                for (int j = 0; j < 8; ++j) a[j] *= r;
            }
            short8v w;
            #pragma unroll
            for (int j = 0; j < 8; ++j) w[j] = (short)f2bf(a[j]);
            uint sw = ((uint)row & 7u) << 4;
            uint addr = (uint)(row * 256 + l16 * 16);
            *(short8v*)((char*)sm + (addr ^ sw)) = w;
        }
    }

    int lane = tid & 63;
    int wid = tid >> 6;
    int wr = wid & 1;        // row half
    int wc = wid >> 1;       // col quarter (64 cols)
    int l15 = lane & 15;
    int lg = lane >> 4;      // k-group

    // ---- x-half MFMA: A-fragments straight from global (before barrier,
    //      overlaps other waves still gathering) ----
    int arow = wr * 16 + l15;
    int grow = r0 + arow;
    const short8v zero8 = (short8v)0;
    bf16x8 ax[4];
    {
        const ushort* xrow = xb + (size_t)grow * 128 + lg * 8;
        #pragma unroll
        for (int ks = 0; ks < 4; ++ks) {
            short8v t = (grow < N) ? *(const short8v*)(xrow + ks * 32) : zero8;
            ax[ks] = __builtin_bit_cast(bf16x8, t);
        }
    }
    f32x4 acc[4];
    #pragma unroll
    for (int ct = 0; ct < 4; ++ct) acc[ct] = (f32x4)0.f;
    #pragma unroll
    for (int ct = 0; ct < 4; ++ct) {
        int bcol = wc * 64 + ct * 16 + l15;
        const ushort* bp = Bt + bcol * 256 + lg * 8;
        #pragma unroll
        for (int ks = 0; ks < 4; ++ks) {
            bf16x8 b = *(const bf16x8*)(bp + ks * 32);
            acc[ct] = __builtin_amdgcn_mfma_f32_16x16x32_bf16(ax[ks], b, acc[ct], 0, 0, 0);
        }
    }
    __syncthreads();

    // ---- mean-half MFMA from LDS ----
    uint abase = (uint)(arow * 256 + lg * 16);
    uint asw = ((uint)arow & 7u) << 4;
    bf16x8 am[4];
    #pragma unroll
    for (int ks = 0; ks < 4; ++ks) {
        am[ks] = *(const bf16x8*)((const char*)sm + ((abase + (uint)ks * 64) ^ asw));
    }
    #pragma unroll
    for (int ct = 0; ct < 4; ++ct) {
        int bcol = wc * 64 + ct * 16 + l15;
        const ushort* bp = Bt + bcol * 256 + 128 + lg * 8;
        #pragma unroll
        for (int ks = 0; ks < 4; ++ks) {
            bf16x8 b = *(const bf16x8*)(bp + ks * 32);
            acc[ct] = __builtin_amdgcn_mfma_f32_16x16x32_bf16(am[ks], b, acc[ct], 0, 0, 0);
        }
    }

    // ---- epilogue: C/D layout col=lane&15, row=(lane>>4)*4+r ----
    int crow = r0 + wr * 16 + lg * 4;
    #pragma unroll
    for (int ct = 0; ct < 4; ++ct) {
        int col = wc * 64 + ct * 16 + l15;
        float bv = bias[col];
        #pragma unroll
        for (int r = 0; r < 4; ++r) {
            int row = crow + r;
            if (row < N) {
                float v = acc[ct][r] + bv;
                if (RELU) v = fmaxf(v, 0.f);
                if (OUTBF) ((ushort*)outp)[(size_t)row * 128 + col] = f2bf(v);
                else       ((float*)outp)[(size_t)row * 128 + col] = v;
            }
        }
    }
}

// ---------------- launch ----------------

extern "C" void kernel_launch(void* const* d_in, const int* in_sizes, int n_in,
                              void* d_out, int out_size, void* d_ws, size_t ws_size,
                              hipStream_t stream) {
    const float* feat = (const float*)d_in[0];
    const int* src = (const int*)d_in[1];
    const int* dst = (const int*)d_in[2];
    const float* W1s = (const float*)d_in[3];
    const float* W1n = (const float*)d_in[4];
    const float* b1 = (const float*)d_in[5];
    const float* W2s = (const float*)d_in[6];
    const float* W2n = (const float*)d_in[7];
    const float* b2 = (const float*)d_in[8];
    const float* W3s = (const float*)d_in[9];
    const float* W3n = (const float*)d_in[10];
    const float* b3 = (const float*)d_in[11];
    float* out = (float*)d_out;

    const int N = NN, E = NE;
    const int NB = (N + 1023) / 1024;

    char* p = (char*)d_ws;
    auto alloc = [&](size_t bytes) {
        char* q = p;
        p += (bytes + 255) & ~(size_t)255;
        return q;
    };
    int* deg = (int*)alloc((size_t)N * 4);
    int* off = (int*)alloc((size_t)N * 4);
    int* cur = (int*)alloc((size_t)N * 4);
    float* recip = (float*)alloc((size_t)N * 4);
    int* bsum = (int*)alloc(64 * 4);
    int* csr = (int*)alloc((size_t)E * 4);
    ushort* xb0 = (ushort*)alloc((size_t)N * F * 2);
    ushort* h1b = (ushort*)alloc((size_t)N * F * 2);
    ushort* h2b = (ushort*)alloc((size_t)N * F * 2);
    ushort* Bt1 = (ushort*)alloc(128 * 256 * 2);
    ushort* Bt2 = (ushort*)alloc(128 * 256 * 2);
    ushort* Bt3 = (ushort*)alloc(128 * 256 * 2);

    wt_prep<<<dim3(128, 3), 256, 0, stream>>>(W1s, W1n, W2s, W2n, W3s, W3n, Bt1, Bt2, Bt3);
    to_bf16<<<(N * F / 8 + 255) / 256, 256, 0, stream>>>(feat, xb0, N * F / 8);

    hipMemsetAsync(deg, 0, (size_t)N * 4, stream);
    count_deg<<<(E + 255) / 256, 256, 0, stream>>>(dst, deg, E);
    scan_part1<<<NB, 1024, 0, stream>>>(deg, bsum, N);
    scan_part3<<<NB, 1024, 0, stream>>>(deg, bsum, off, cur, recip, N, NB);
    fill_csr<<<(E + 255) / 256, 256, 0, stream>>>(src, dst, cur, csr, E);

    int grid = (N + 31) / 32;

    sage_layer<1, 1><<<grid, 256, 0, stream>>>(xb0, off, deg, recip, csr, Bt1, b1, h1b, N);
    sage_layer<1, 1><<<grid, 256, 0, stream>>>(h1b, off, deg, recip, csr, Bt2, b2, h2b, N);
    sage_layer<0, 0><<<grid, 256, 0, stream>>>(h2b, off, deg, recip, csr, Bt3, b3, out, N);
}

// Round 18
// 236.310 us; speedup vs baseline: 1.1444x; 1.0235x over previous
//
#include <hip/hip_runtime.h>

#define NN 50000
#define NE 600000
#define F 128

typedef __attribute__((ext_vector_type(4))) float f4;
typedef __attribute__((ext_vector_type(4))) float f32x4;
typedef __bf16 bf16x8 __attribute__((ext_vector_type(8)));
typedef short short8v __attribute__((ext_vector_type(8)));
typedef unsigned short u16x8 __attribute__((ext_vector_type(8)));

__device__ inline ushort f2bf(float f) {
    uint u = __builtin_bit_cast(uint, f);
    uint r = (u + 0x7FFFu + ((u >> 16) & 1u)) >> 16;
    return (ushort)r;
}
__device__ inline float bf2f(ushort u) {
    uint t = ((uint)u) << 16;
    return __builtin_bit_cast(float, t);
}

// ---------------- graph prep ----------------

__global__ void count_deg(const int* __restrict__ dst, int* __restrict__ deg, int E) {
    int e = blockIdx.x * blockDim.x + threadIdx.x;
    if (e < E) atomicAdd(&deg[dst[e]], 1);
}

__global__ __launch_bounds__(1024) void scan_part1(const int* __restrict__ deg,
                                                   int* __restrict__ bsum, int N) {
    __shared__ int ws[16];
    int tid = threadIdx.x;
    int idx = blockIdx.x * 1024 + tid;
    int v = (idx < N) ? deg[idx] : 0;
    #pragma unroll
    for (int o = 32; o; o >>= 1) v += __shfl_down(v, o);
    if ((tid & 63) == 0) ws[tid >> 6] = v;
    __syncthreads();
    if (tid < 64) {
        int t = (tid < 16) ? ws[tid] : 0;
        #pragma unroll
        for (int o = 8; o; o >>= 1) t += __shfl_down(t, o);
        if (tid == 0) bsum[blockIdx.x] = t;
    }
}

__global__ __launch_bounds__(1024) void scan_part3(const int* __restrict__ deg,
                                                   const int* __restrict__ bsum,
                                                   int* __restrict__ off,
                                                   int* __restrict__ cur,
                                                   float* __restrict__ recip,
                                                   int N, int NB) {
    __shared__ int wsum[16];
    __shared__ int sbase;
    int tid = threadIdx.x;
    int wid = tid >> 6;
    int lane = tid & 63;
    if (tid < 64) {
        int v = (tid < NB) ? bsum[tid] : 0;
        int x = v;
        #pragma unroll
        for (int o = 1; o < 64; o <<= 1) {
            int t = __shfl_up(x, o);
            if (lane >= o) x += t;
        }
        if (tid == blockIdx.x) sbase = x - v;
    }
    int idx = blockIdx.x * 1024 + tid;
    int v = (idx < N) ? deg[idx] : 0;
    int x = v;
    #pragma unroll
    for (int o = 1; o < 64; o <<= 1) {
        int t = __shfl_up(x, o);
        if (lane >= o) x += t;
    }
    if (lane == 63) wsum[wid] = x;
    __syncthreads();
    if (tid == 0) {
        int a = 0;
        #pragma unroll
        for (int w = 0; w < 16; ++w) { int t = wsum[w]; wsum[w] = a; a += t; }
    }
    __syncthreads();
    int incl = x + wsum[wid];
    if (idx < N) {
        int start = sbase + incl - v;
        off[idx] = start;
        cur[idx] = start;
        recip[idx] = 1.0f / (float)max(v, 1);
    }
}

__global__ void fill_csr(const int* __restrict__ src, const int* __restrict__ dst,
                         int* __restrict__ cur, int* __restrict__ csr, int E) {
    int e = blockIdx.x * blockDim.x + threadIdx.x;
    if (e < E) {
        int pos = atomicAdd(&cur[dst[e]], 1);
        csr[pos] = src[e];
    }
}

// ---------------- weight prep: Bt[col][k] bf16 for all 3 layers ----------------

__global__ __launch_bounds__(256) void wt_prep(const float* __restrict__ W1s, const float* __restrict__ W1n,
                                               const float* __restrict__ W2s, const float* __restrict__ W2n,
                                               const float* __restrict__ W3s, const float* __restrict__ W3n,
                                               ushort* __restrict__ Bt1, ushort* __restrict__ Bt2,
                                               ushort* __restrict__ Bt3) {
    int layer = blockIdx.y;
    const float* Ws = (layer == 0) ? W1s : (layer == 1) ? W2s : W3s;
    const float* Wn = (layer == 0) ? W1n : (layer == 1) ? W2n : W3n;
    ushort* Bt = (layer == 0) ? Bt1 : (layer == 1) ? Bt2 : Bt3;
    int col = blockIdx.x;
    int k = threadIdx.x;
    float v = (k < 128) ? Ws[k * 128 + col] : Wn[(k - 128) * 128 + col];
    Bt[col * 256 + k] = f2bf(v);
}

// ---------------- f32 -> bf16 feature convert ----------------

__global__ __launch_bounds__(256) void to_bf16(const float* __restrict__ in,
                                               ushort* __restrict__ out, int n8) {
    int i = blockIdx.x * 256 + threadIdx.x;
    if (i < n8) {
        const f4* p = (const f4*)in + (size_t)i * 2;
        f4 a = p[0], b = p[1];
        short8v w;
        w[0] = (short)f2bf(a[0]); w[1] = (short)f2bf(a[1]);
        w[2] = (short)f2bf(a[2]); w[3] = (short)f2bf(a[3]);
        w[4] = (short)f2bf(b[0]); w[5] = (short)f2bf(b[1]);
        w[6] = (short)f2bf(b[2]); w[7] = (short)f2bf(b[3]);
        ((short8v*)out)[i] = w;
    }
}

// ---------------- fused SAGE layer with DUAL-round-1 gather/MFMA overlap ----------------
// 32 nodes x 128 cols per block, 256 threads (4 waves). K split: ks 0..3 use
// staged x (k 0..127), ks 4..7 use gathered mean (k 128..255). Schedule:
// stage x -> barrier -> issue round-1 loads for BOTH nodes A (row g) and
// B (row g+16): 16 independent 16B loads in flight -> x-half MFMAs hide that
// latency -> finish A (acc r1 + tail rounds) -> finish B -> barrier ->
// mean-half MFMAs -> epilogue.

template <int RELU, int OUTBF>
__global__ __launch_bounds__(256) void sage_layer(const ushort* __restrict__ xb,
                                                  const int* __restrict__ off,
                                                  const int* __restrict__ deg,
                                                  const float* __restrict__ recip,
                                                  const int* __restrict__ csr,
                                                  const ushort* __restrict__ Bt,
                                                  const float* __restrict__ bias,
                                                  void* __restrict__ outp, int N) {
    __shared__ ushort sa[32 * 256];  // 16 KB, [row][k], XOR-swizzled
    int tid = threadIdx.x;
    int r0 = blockIdx.x * 32;

    // ---- stage x rows (k 0..127): 32 B per thread ----
    {
        int row = tid >> 3;
        int c = tid & 7;
        int grow = r0 + row;
        uint sw = ((uint)row & 7u) << 4;
        uint base = (uint)(row * 512 + c * 32);
        short8v w0 = (short8v)0, w1 = (short8v)0;
        if (grow < N) {
            const short8v* sp = (const short8v*)&xb[(size_t)grow * 128 + c * 16];
            w0 = sp[0]; w1 = sp[1];
        }
        *(short8v*)((char*)sa + (base ^ sw)) = w0;
        *(short8v*)((char*)sa + ((base + 16) ^ sw)) = w1;
    }
    __syncthreads();

    int lane = tid & 63;
    int wid = tid >> 6;
    int wr = wid & 1;        // row half for MFMA
    int wc = wid >> 1;       // col quarter (64 cols)
    int l15 = lane & 15;
    int lg = lane >> 4;      // k-group
    int l16 = tid & 15;      // gather lane
    int g = tid >> 4;        // gather group 0..15

    const ushort* xpb = xb + (size_t)l16 * 8;

    // ---- issue round-1 gather loads for node A (row g) ----
    int nodeA = r0 + g;
    int startA = 0, dA = 0;
    float rA = 0.f;
    if (nodeA < N) { startA = off[nodeA]; dA = deg[nodeA]; rA = recip[nodeA]; }
    int dm1A = (dA > 0) ? dA - 1 : 0;
    int baseA = (dA > 0) ? startA : 0;
    u16x8 vA[8];
    {
        int s[8];
        #pragma unroll
        for (int u = 0; u < 8; ++u) {
            int idx = (u < dm1A) ? u : dm1A;
            s[u] = csr[baseA + idx];
        }
        #pragma unroll
        for (int u = 0; u < 8; ++u) vA[u] = *(const u16x8*)(xpb + (size_t)s[u] * 128);
    }

    // ---- issue round-1 gather loads for node B (row g+16) ----
    int rowB = g + 16;
    int nodeB = r0 + rowB;
    int startB = 0, dB = 0;
    float rB = 0.f;
    if (nodeB < N) { startB = off[nodeB]; dB = deg[nodeB]; rB = recip[nodeB]; }
    int dm1B = (dB > 0) ? dB - 1 : 0;
    int baseB = (dB > 0) ? startB : 0;
    u16x8 vB[8];
    {
        int s[8];
        #pragma unroll
        for (int u = 0; u < 8; ++u) {
            int idx = (u < dm1B) ? u : dm1B;
            s[u] = csr[baseB + idx];
        }
        #pragma unroll
        for (int u = 0; u < 8; ++u) vB[u] = *(const u16x8*)(xpb + (size_t)s[u] * 128);
    }

    // ---- x-half MFMAs while both round-1 gathers are in flight ----
    int arow = wr * 16 + l15;
    uint abase = (uint)(arow * 512 + lg * 16);
    uint asw = ((uint)arow & 7u) << 4;
    bf16x8 ax[4];
    #pragma unroll
    for (int ks = 0; ks < 4; ++ks) {
        ax[ks] = *(const bf16x8*)((const char*)sa + ((abase + (uint)ks * 64) ^ asw));
    }
    f32x4 acc[4];
    #pragma unroll
    for (int ct = 0; ct < 4; ++ct) acc[ct] = (f32x4)0.f;
    #pragma unroll
    for (int ct = 0; ct < 4; ++ct) {
        int bcol = wc * 64 + ct * 16 + l15;
        const ushort* bp = Bt + bcol * 256 + lg * 8;
        #pragma unroll
        for (int ks = 0; ks < 4; ++ks) {
            bf16x8 b = *(const bf16x8*)(bp + ks * 32);
            acc[ct] = __builtin_amdgcn_mfma_f32_16x16x32_bf16(ax[ks], b, acc[ct], 0, 0, 0);
        }
    }

    // ---- finish gather node A ----
    {
        float a[8] = {0.f, 0.f, 0.f, 0.f, 0.f, 0.f, 0.f, 0.f};
        #pragma unroll
        for (int u = 0; u < 8; ++u) {
            float m = (u < dA) ? 1.f : 0.f;
            #pragma unroll
            for (int j = 0; j < 8; ++j) a[j] += m * bf2f(vA[u][j]);
        }
        for (int i = 8; i < dA; i += 8) {
            int s[8];
            #pragma unroll
            for (int u = 0; u < 8; ++u) {
                int idx = i + u;
                s[u] = csr[baseA + ((idx < dm1A) ? idx : dm1A)];
            }
            u16x8 v[8];
            #pragma unroll
            for (int u = 0; u < 8; ++u) v[u] = *(const u16x8*)(xpb + (size_t)s[u] * 128);
            #pragma unroll
            for (int u = 0; u < 8; ++u) {
                float m = (i + u < dA) ? 1.f : 0.f;
                #pragma unroll
                for (int j = 0; j < 8; ++j) a[j] += m * bf2f(v[u][j]);
            }
        }
        short8v w;
        #pragma unroll
        for (int j = 0; j < 8; ++j) w[j] = (short)f2bf(a[j] * rA);
        uint sw = ((uint)g & 7u) << 4;
        uint addr = (uint)(g * 512 + 256 + l16 * 16);
        *(short8v*)((char*)sa + (addr ^ sw)) = w;
    }

    // ---- finish gather node B ----
    {
        float a[8] = {0.f, 0.f, 0.f, 0.f, 0.f, 0.f, 0.f, 0.f};
        #pragma unroll
        for (int u = 0; u < 8; ++u) {
            float m = (u < dB) ? 1.f : 0.f;
            #pragma unroll
            for (int j = 0; j < 8; ++j) a[j] += m * bf2f(vB[u][j]);
        }
        for (int i = 8; i < dB; i += 8) {
            int s[8];
            #pragma unroll
            for (int u = 0; u < 8; ++u) {
                int idx = i + u;
                s[u] = csr[baseB + ((idx < dm1B) ? idx : dm1B)];
            }
            u16x8 v[8];
            #pragma unroll
            for (int u = 0; u < 8; ++u) v[u] = *(const u16x8*)(xpb + (size_t)s[u] * 128);
            #pragma unroll
            for (int u = 0; u < 8; ++u) {
                float m = (i + u < dB) ? 1.f : 0.f;
                #pragma unroll
                for (int j = 0; j < 8; ++j) a[j] += m * bf2f(v[u][j]);
            }
        }
        short8v w;
        #pragma unroll
        for (int j = 0; j < 8; ++j) w[j] = (short)f2bf(a[j] * rB);
        uint sw = ((uint)rowB & 7u) << 4;
        uint addr = (uint)(rowB * 512 + 256 + l16 * 16);
        *(short8v*)((char*)sa + (addr ^ sw)) = w;
    }
    __syncthreads();

    // ---- mean-half MFMAs (k 128..255) ----
    bf16x8 am[4];
    #pragma unroll
    for (int ks = 0; ks < 4; ++ks) {
        am[ks] = *(const bf16x8*)((const char*)sa + ((abase + 256u + (uint)ks * 64) ^ asw));
    }
    #pragma unroll
    for (int ct = 0; ct < 4; ++ct) {
        int bcol = wc * 64 + ct * 16 + l15;
        const ushort* bp = Bt + bcol * 256 + 128 + lg * 8;
        #pragma unroll
        for (int ks = 0; ks < 4; ++ks) {
            bf16x8 b = *(const bf16x8*)(bp + ks * 32);
            acc[ct] = __builtin_amdgcn_mfma_f32_16x16x32_bf16(am[ks], b, acc[ct], 0, 0, 0);
        }
    }

    // ---- epilogue: C/D layout col=lane&15, row=(lane>>4)*4+r ----
    int crow = r0 + wr * 16 + lg * 4;
    #pragma unroll
    for (int ct = 0; ct < 4; ++ct) {
        int col = wc * 64 + ct * 16 + l15;
        float bv = bias[col];
        #pragma unroll
        for (int r = 0; r < 4; ++r) {
            int row = crow + r;
            if (row < N) {
                float v = acc[ct][r] + bv;
                if (RELU) v = fmaxf(v, 0.f);
                if (OUTBF) ((ushort*)outp)[(size_t)row * 128 + col] = f2bf(v);
                else       ((float*)outp)[(size_t)row * 128 + col] = v;
            }
        }
    }
}

// ---------------- launch ----------------

extern "C" void kernel_launch(void* const* d_in, const int* in_sizes, int n_in,
                              void* d_out, int out_size, void* d_ws, size_t ws_size,
                              hipStream_t stream) {
    const float* feat = (const float*)d_in[0];
    const int* src = (const int*)d_in[1];
    const int* dst = (const int*)d_in[2];
    const float* W1s = (const float*)d_in[3];
    const float* W1n = (const float*)d_in[4];
    const float* b1 = (const float*)d_in[5];
    const float* W2s = (const float*)d_in[6];
    const float* W2n = (const float*)d_in[7];
    const float* b2 = (const float*)d_in[8];
    const float* W3s = (const float*)d_in[9];
    const float* W3n = (const float*)d_in[10];
    const float* b3 = (const float*)d_in[11];
    float* out = (float*)d_out;

    const int N = NN, E = NE;
    const int NB = (N + 1023) / 1024;

    char* p = (char*)d_ws;
    auto alloc = [&](size_t bytes) {
        char* q = p;
        p += (bytes + 255) & ~(size_t)255;
        return q;
    };
    int* deg = (int*)alloc((size_t)N * 4);
    int* off = (int*)alloc((size_t)N * 4);
    int* cur = (int*)alloc((size_t)N * 4);
    float* recip = (float*)alloc((size_t)N * 4);
    int* bsum = (int*)alloc(64 * 4);
    int* csr = (int*)alloc((size_t)E * 4);
    ushort* xb0 = (ushort*)alloc((size_t)N * F * 2);
    ushort* h1b = (ushort*)alloc((size_t)N * F * 2);
    ushort* h2b = (ushort*)alloc((size_t)N * F * 2);
    ushort* Bt1 = (ushort*)alloc(128 * 256 * 2);
    ushort* Bt2 = (ushort*)alloc(128 * 256 * 2);
    ushort* Bt3 = (ushort*)alloc(128 * 256 * 2);

    wt_prep<<<dim3(128, 3), 256, 0, stream>>>(W1s, W1n, W2s, W2n, W3s, W3n, Bt1, Bt2, Bt3);
    to_bf16<<<(N * F / 8 + 255) / 256, 256, 0, stream>>>(feat, xb0, N * F / 8);

    hipMemsetAsync(deg, 0, (size_t)N * 4, stream);
    count_deg<<<(E + 255) / 256, 256, 0, stream>>>(dst, deg, E);
    scan_part1<<<NB, 1024, 0, stream>>>(deg, bsum, N);
    scan_part3<<<NB, 1024, 0, stream>>>(deg, bsum, off, cur, recip, N, NB);
    fill_csr<<<(E + 255) / 256, 256, 0, stream>>>(src, dst, cur, csr, E);

    int grid = (N + 31) / 32;

    sage_layer<1, 1><<<grid, 256, 0, stream>>>(xb0, off, deg, recip, csr, Bt1, b1, h1b, N);
    sage_layer<1, 1><<<grid, 256, 0, stream>>>(h1b, off, deg, recip, csr, Bt2, b2, h2b, N);
    sage_layer<0, 0><<<grid, 256, 0, stream>>>(h2b, off, deg, recip, csr, Bt3, b3, out, N);
}

// Round 19
// 232.194 us; speedup vs baseline: 1.1647x; 1.0177x over previous
//
#include <hip/hip_runtime.h>

#define NN 50000
#define NE 600000
#define F 128

typedef __attribute__((ext_vector_type(4))) float f4;
typedef __attribute__((ext_vector_type(4))) float f32x4;
typedef __bf16 bf16x8 __attribute__((ext_vector_type(8)));
typedef short short8v __attribute__((ext_vector_type(8)));
typedef unsigned short u16x8 __attribute__((ext_vector_type(8)));

__device__ inline ushort f2bf(float f) {
    uint u = __builtin_bit_cast(uint, f);
    uint r = (u + 0x7FFFu + ((u >> 16) & 1u)) >> 16;
    return (ushort)r;
}
__device__ inline float bf2f(ushort u) {
    uint t = ((uint)u) << 16;
    return __builtin_bit_cast(float, t);
}

// ---------------- graph prep ----------------

__global__ void count_deg(const int* __restrict__ dst, int* __restrict__ deg, int E) {
    int e = blockIdx.x * blockDim.x + threadIdx.x;
    if (e < E) atomicAdd(&deg[dst[e]], 1);
}

__global__ __launch_bounds__(1024) void scan_part1(const int* __restrict__ deg,
                                                   int* __restrict__ bsum, int N) {
    __shared__ int ws[16];
    int tid = threadIdx.x;
    int idx = blockIdx.x * 1024 + tid;
    int v = (idx < N) ? deg[idx] : 0;
    #pragma unroll
    for (int o = 32; o; o >>= 1) v += __shfl_down(v, o);
    if ((tid & 63) == 0) ws[tid >> 6] = v;
    __syncthreads();
    if (tid < 64) {
        int t = (tid < 16) ? ws[tid] : 0;
        #pragma unroll
        for (int o = 8; o; o >>= 1) t += __shfl_down(t, o);
        if (tid == 0) bsum[blockIdx.x] = t;
    }
}

// pass 2+3 fused: every block scans bsum redundantly in wave 0, then local scan
__global__ __launch_bounds__(1024) void scan_part3(const int* __restrict__ deg,
                                                   const int* __restrict__ bsum,
                                                   int* __restrict__ off,
                                                   int* __restrict__ cur,
                                                   float* __restrict__ recip,
                                                   int N, int NB) {
    __shared__ int wsum[16];
    __shared__ int sbase;
    int tid = threadIdx.x;
    int wid = tid >> 6;
    int lane = tid & 63;
    if (tid < 64) {
        int v = (tid < NB) ? bsum[tid] : 0;
        int x = v;
        #pragma unroll
        for (int o = 1; o < 64; o <<= 1) {
            int t = __shfl_up(x, o);
            if (lane >= o) x += t;
        }
        if (tid == blockIdx.x) sbase = x - v;
    }
    int idx = blockIdx.x * 1024 + tid;
    int v = (idx < N) ? deg[idx] : 0;
    int x = v;
    #pragma unroll
    for (int o = 1; o < 64; o <<= 1) {
        int t = __shfl_up(x, o);
        if (lane >= o) x += t;
    }
    if (lane == 63) wsum[wid] = x;
    __syncthreads();
    if (tid == 0) {
        int a = 0;
        #pragma unroll
        for (int w = 0; w < 16; ++w) { int t = wsum[w]; wsum[w] = a; a += t; }
    }
    __syncthreads();
    int incl = x + wsum[wid];
    if (idx < N) {
        int start = sbase + incl - v;
        off[idx] = start;
        cur[idx] = start;
        recip[idx] = 1.0f / (float)max(v, 1);
    }
}

__global__ void fill_csr(const int* __restrict__ src, const int* __restrict__ dst,
                         int* __restrict__ cur, int* __restrict__ csr, int E) {
    int e = blockIdx.x * blockDim.x + threadIdx.x;
    if (e < E) {
        int pos = atomicAdd(&cur[dst[e]], 1);
        csr[pos] = src[e];
    }
}

// ---------------- weight prep: Bt[col][k] bf16 for all 3 layers ----------------

__global__ __launch_bounds__(256) void wt_prep(const float* __restrict__ W1s, const float* __restrict__ W1n,
                                               const float* __restrict__ W2s, const float* __restrict__ W2n,
                                               const float* __restrict__ W3s, const float* __restrict__ W3n,
                                               ushort* __restrict__ Bt1, ushort* __restrict__ Bt2,
                                               ushort* __restrict__ Bt3) {
    int layer = blockIdx.y;
    const float* Ws = (layer == 0) ? W1s : (layer == 1) ? W2s : W3s;
    const float* Wn = (layer == 0) ? W1n : (layer == 1) ? W2n : W3n;
    ushort* Bt = (layer == 0) ? Bt1 : (layer == 1) ? Bt2 : Bt3;
    int col = blockIdx.x;
    int k = threadIdx.x;
    float v = (k < 128) ? Ws[k * 128 + col] : Wn[(k - 128) * 128 + col];
    Bt[col * 256 + k] = f2bf(v);
}

// ---------------- f32 -> bf16 feature convert ----------------

__global__ __launch_bounds__(256) void to_bf16(const float* __restrict__ in,
                                               ushort* __restrict__ out, int n8) {
    int i = blockIdx.x * 256 + threadIdx.x;
    if (i < n8) {
        const f4* p = (const f4*)in + (size_t)i * 2;
        f4 a = p[0], b = p[1];
        short8v w;
        w[0] = (short)f2bf(a[0]); w[1] = (short)f2bf(a[1]);
        w[2] = (short)f2bf(a[2]); w[3] = (short)f2bf(a[3]);
        w[4] = (short)f2bf(b[0]); w[5] = (short)f2bf(b[1]);
        w[6] = (short)f2bf(b[2]); w[7] = (short)f2bf(b[3]);
        ((short8v*)out)[i] = w;
    }
}

// ---------------- fused SAGE layer: out = act([x | mean(x,nbrs)] @ Bt^T + b) ----------------
// 16 nodes x 128 cols per block (3125 blocks), 256 threads (4 waves).
// Phase 1: stage x rows (k 0..127) into swizzled LDS; gather-mean neighbors
// (16 lanes/node, 16B u16x8 loads, f32 accum) with intra-block work
// distribution (LDS counter) , result written to LDS (k 128..255).
// Phase 2: per wave 2 col-tiles x 8 k-steps of mfma_f32_16x16x32_bf16.
// Output bf16 (layers 1,2) or f32 (layer 3). No aliasing: out != xb.

template <int RELU, int OUTBF>
__global__ __launch_bounds__(256) void sage_layer(const ushort* __restrict__ xb,
                                                  const int* __restrict__ off,
                                                  const int* __restrict__ deg,
                                                  const float* __restrict__ recip,
                                                  const int* __restrict__ csr,
                                                  const ushort* __restrict__ Bt,
                                                  const float* __restrict__ bias,
                                                  void* __restrict__ outp, int N) {
    __shared__ ushort sa[16 * 256];  // 8 KB, [row][k], XOR-swizzled
    __shared__ int wcnt;
    int tid = threadIdx.x;
    int r0 = blockIdx.x * 16;
    if (tid == 0) wcnt = 0;

    // ---- stage x rows (k 0..127): one 16B chunk per thread ----
    {
        int row = tid >> 4;      // 0..15
        int c = tid & 15;        // 16 B chunk
        int grow = r0 + row;
        uint sw = ((uint)row & 7u) << 4;
        uint base = (uint)(row * 512 + c * 16);
        short8v w = (short8v)0;
        if (grow < N) w = ((const short8v*)&xb[(size_t)grow * 128])[c];
        *(short8v*)((char*)sa + (base ^ sw)) = w;
    }
    __syncthreads();  // wcnt init visible

    // ---- gather-mean into LDS (k 128..255): 16 lanes/node, work-stealing ----
    {
        int l16 = tid & 15;
        int lanebase = (tid & 63) & ~15;   // this group's lane 0 within wave
        const ushort* xpb = xb + (size_t)l16 * 8;  // this lane's 8-col slice
        for (;;) {
            int n = 0;
            if (l16 == 0) n = atomicAdd(&wcnt, 1);
            n = __shfl(n, lanebase);
            if (n >= 16) break;
            int row = n;
            int node = r0 + row;
            float a[8] = {0.f, 0.f, 0.f, 0.f, 0.f, 0.f, 0.f, 0.f};
            if (node < N) {
                int start = off[node];
                int d = deg[node];
                int nfull = d & ~7;
                int i = 0;
                for (; i < nfull; i += 8) {
                    int s[8];
                    #pragma unroll
                    for (int u = 0; u < 8; ++u) s[u] = csr[start + i + u];
                    u16x8 v[8];
                    #pragma unroll
                    for (int u = 0; u < 8; ++u) v[u] = *(const u16x8*)(xpb + (size_t)s[u] * 128);
                    #pragma unroll
                    for (int u = 0; u < 8; ++u) {
                        #pragma unroll
                        for (int j = 0; j < 8; ++j) a[j] += bf2f(v[u][j]);
                    }
                }
                if (i < d) {
                    int dm1 = d - 1;
                    int s[8];
                    #pragma unroll
                    for (int u = 0; u < 8; ++u) {
                        int idx = i + u;
                        s[u] = csr[start + ((idx < dm1) ? idx : dm1)];
                    }
                    u16x8 v[8];
                    #pragma unroll
                    for (int u = 0; u < 8; ++u) v[u] = *(const u16x8*)(xpb + (size_t)s[u] * 128);
                    #pragma unroll
                    for (int u = 0; u < 8; ++u) {
                        float m = (i + u < d) ? 1.f : 0.f;
                        #pragma unroll
                        for (int j = 0; j < 8; ++j) a[j] += m * bf2f(v[u][j]);
                    }
                }
                float r = recip[node];
                #pragma unroll
                for (int j = 0; j < 8; ++j) a[j] *= r;
            }
            short8v w;
            #pragma unroll
            for (int j = 0; j < 8; ++j) w[j] = (short)f2bf(a[j]);
            uint sw = ((uint)row & 7u) << 4;
            uint addr = (uint)(row * 512 + 256 + l16 * 16);
            *(short8v*)((char*)sa + (addr ^ sw)) = w;
        }
    }
    __syncthreads();

    int lane = tid & 63;
    int wid = tid >> 6;      // col block of 32
    int l15 = lane & 15;
    int lg = lane >> 4;      // k-group

    // ---- A fragments (8 k-steps), M=16 ----
    uint abase = (uint)(l15 * 512 + lg * 16);
    uint asw = ((uint)l15 & 7u) << 4;
    bf16x8 a[8];
    #pragma unroll
    for (int ks = 0; ks < 8; ++ks) {
        a[ks] = *(const bf16x8*)((const char*)sa + ((abase + (uint)ks * 64) ^ asw));
    }

    // ---- MFMA: 2 col-tiles x 8 k-steps per wave ----
    f32x4 acc[2];
    #pragma unroll
    for (int ct = 0; ct < 2; ++ct) acc[ct] = (f32x4)0.f;

    #pragma unroll
    for (int ct = 0; ct < 2; ++ct) {
        int bcol = wid * 32 + ct * 16 + l15;
        const ushort* bp = Bt + bcol * 256 + lg * 8;
        #pragma unroll
        for (int ks = 0; ks < 8; ++ks) {
            bf16x8 b = *(const bf16x8*)(bp + ks * 32);
            acc[ct] = __builtin_amdgcn_mfma_f32_16x16x32_bf16(a[ks], b, acc[ct], 0, 0, 0);
        }
    }

    // ---- epilogue: C/D layout col=lane&15, row=(lane>>4)*4+r ----
    int crow = r0 + lg * 4;
    #pragma unroll
    for (int ct = 0; ct < 2; ++ct) {
        int col = wid * 32 + ct * 16 + l15;
        float bv = bias[col];
        #pragma unroll
        for (int r = 0; r < 4; ++r) {
            int row = crow + r;
            if (row < N) {
                float v = acc[ct][r] + bv;
                if (RELU) v = fmaxf(v, 0.f);
                if (OUTBF) ((ushort*)outp)[(size_t)row * 128 + col] = f2bf(v);
                else       ((float*)outp)[(size_t)row * 128 + col] = v;
            }
        }
    }
}

// ---------------- launch ----------------

extern "C" void kernel_launch(void* const* d_in, const int* in_sizes, int n_in,
                              void* d_out, int out_size, void* d_ws, size_t ws_size,
                              hipStream_t stream) {
    const float* feat = (const float*)d_in[0];
    const int* src = (const int*)d_in[1];
    const int* dst = (const int*)d_in[2];
    const float* W1s = (const float*)d_in[3];
    const float* W1n = (const float*)d_in[4];
    const float* b1 = (const float*)d_in[5];
    const float* W2s = (const float*)d_in[6];
    const float* W2n = (const float*)d_in[7];
    const float* b2 = (const float*)d_in[8];
    const float* W3s = (const float*)d_in[9];
    const float* W3n = (const float*)d_in[10];
    const float* b3 = (const float*)d_in[11];
    float* out = (float*)d_out;

    const int N = NN, E = NE;
    const int NB = (N + 1023) / 1024;  // 49 scan blocks

    char* p = (char*)d_ws;
    auto alloc = [&](size_t bytes) {
        char* q = p;
        p += (bytes + 255) & ~(size_t)255;
        return q;
    };
    int* deg = (int*)alloc((size_t)N * 4);
    int* off = (int*)alloc((size_t)N * 4);
    int* cur = (int*)alloc((size_t)N * 4);
    float* recip = (float*)alloc((size_t)N * 4);
    int* bsum = (int*)alloc(64 * 4);
    int* csr = (int*)alloc((size_t)E * 4);
    ushort* xb0 = (ushort*)alloc((size_t)N * F * 2);
    ushort* h1b = (ushort*)alloc((size_t)N * F * 2);
    ushort* h2b = (ushort*)alloc((size_t)N * F * 2);
    ushort* Bt1 = (ushort*)alloc(128 * 256 * 2);
    ushort* Bt2 = (ushort*)alloc(128 * 256 * 2);
    ushort* Bt3 = (ushort*)alloc(128 * 256 * 2);

    wt_prep<<<dim3(128, 3), 256, 0, stream>>>(W1s, W1n, W2s, W2n, W3s, W3n, Bt1, Bt2, Bt3);
    to_bf16<<<(N * F / 8 + 255) / 256, 256, 0, stream>>>(feat, xb0, N * F / 8);

    hipMemsetAsync(deg, 0, (size_t)N * 4, stream);
    count_deg<<<(E + 255) / 256, 256, 0, stream>>>(dst, deg, E);
    scan_part1<<<NB, 1024, 0, stream>>>(deg, bsum, N);
    scan_part3<<<NB, 1024, 0, stream>>>(deg, bsum, off, cur, recip, N, NB);
    fill_csr<<<(E + 255) / 256, 256, 0, stream>>>(src, dst, cur, csr, E);

    int grid = (N + 15) / 16;

    // layer 1
    sage_layer<1, 1><<<grid, 256, 0, stream>>>(xb0, off, deg, recip, csr, Bt1, b1, h1b, N);
    // layer 2
    sage_layer<1, 1><<<grid, 256, 0, stream>>>(h1b, off, deg, recip, csr, Bt2, b2, h2b, N);
    // layer 3 -> f32 d_out
    sage_layer<0, 0><<<grid, 256, 0, stream>>>(h2b, off, deg, recip, csr, Bt3, b3, out, N);
}